// Round 5
// baseline (275.576 us; speedup 1.0000x reference)
//
#include <hip/hip_runtime.h>
#include <stdint.h>
#include <math.h>

typedef float  f32x4  __attribute__((ext_vector_type(4)));
typedef __bf16 bf16x8 __attribute__((ext_vector_type(8)));
typedef __bf16 bf16x4 __attribute__((ext_vector_type(4)));

#define MFMA16(a, b, c) __builtin_amdgcn_mfma_f32_16x16x32_bf16((a), (b), (c), 0, 0, 0)

static constexpr int kT    = 1024;
static constexpr int kLS   = 72;            // padded row stride in bf16 (144 B, 16B-aligned)
static constexpr int kTile = 64 * kLS;      // 4608 el = 9216 B per 64x64 tile
static constexpr size_t kTensorEl    = (size_t)128 * 16 * kTile;   // 9,437,184 el
static constexpr size_t kTensorBytes = kTensorEl * 2;              // 18,874,368 B

__device__ inline void async16(const void* g, void* l) {
  __builtin_amdgcn_global_load_lds(
      (const __attribute__((address_space(1))) void*)g,
      (__attribute__((address_space(3))) void*)l, 16, 0, 0);
}

// ---------------- Prepass: fp32 -> bf16 (Q/K hi+lo split, V hi only) ----------------
// Layout per tensor: [bh 128][tile 16][row 64][kLS 72] bf16. Q pre-scaled by 0.125.
// Q^T/K^T rows = t|s, cols = c (transposed via LDS). V rows = c, cols = s (direct).
__global__ __launch_bounds__(256, 4)
void prepass(const float* __restrict__ qkv,
             __bf16* __restrict__ qh, __bf16* __restrict__ qlo,
             __bf16* __restrict__ kh, __bf16* __restrict__ klo,
             __bf16* __restrict__ vh)
{
  __shared__ float tq[64 * 65];   // fp32 staging for transpose (stride 65: conflict-free)
  __shared__ float tk[64 * 65];
  const int tid = threadIdx.x;
  const int bid = blockIdx.x, bh = bid >> 4, tile = bid & 15;
  const int b = bh >> 4, h = bh & 15, t0 = tile * 64;
  const float* __restrict__ qb = qkv + (size_t)(b * 3072 + h * 64) * kT;
  const float* __restrict__ kb = qkv + (size_t)(b * 3072 + 1024 + h * 64) * kT;
  const float* __restrict__ vb = qkv + (size_t)(b * 3072 + 2048 + h * 64) * kT;
  const size_t tbase = ((size_t)bh * 16 + tile) * kTile;

  // load phase: float4 per thread; V converts+stores directly (t contiguous)
  const int t4   = (tid & 15) * 4;
  const int crow = tid >> 4;
  #pragma unroll
  for (int i = 0; i < 4; ++i) {
    const int c = i * 16 + crow;
    f32x4 q4 = *(const f32x4*)&qb[(size_t)c * kT + t0 + t4];
    q4 *= 0.125f;
    *(f32x4*)&tq[c * 65 + t4] = q4;
    f32x4 k4 = *(const f32x4*)&kb[(size_t)c * kT + t0 + t4];
    *(f32x4*)&tk[c * 65 + t4] = k4;
    f32x4 v4 = *(const f32x4*)&vb[(size_t)c * kT + t0 + t4];
    bf16x4 v4h;
    #pragma unroll
    for (int j = 0; j < 4; ++j) v4h[j] = (__bf16)v4[j];
    *(bf16x4*)&vh[tbase + c * kLS + t4] = v4h;
  }
  __syncthreads();

  // transpose phase: b64 stores, 4 consecutive c per lane; LDS reads 2-way (free)
  const int c0 = tid & 15;
  const int rr = tid >> 4;
  #pragma unroll
  for (int i = 0; i < 4; ++i) {
    const int row = i * 16 + rr;
    bf16x4 qh4, ql4, kh4, kl4;
    #pragma unroll
    for (int j = 0; j < 4; ++j) {
      float q = tq[(c0 * 4 + j) * 65 + row];
      __bf16 qhi = (__bf16)q;
      qh4[j] = qhi; ql4[j] = (__bf16)(q - (float)qhi);
      float k = tk[(c0 * 4 + j) * 65 + row];
      __bf16 khi = (__bf16)k;
      kh4[j] = khi; kl4[j] = (__bf16)(k - (float)khi);
    }
    const size_t o = tbase + row * kLS + c0 * 4;
    *(bf16x4*)&qh [o] = qh4;
    *(bf16x4*)&qlo[o] = ql4;
    *(bf16x4*)&kh [o] = kh4;
    *(bf16x4*)&klo[o] = kl4;
  }
}

// ---------------- Main: flash attention, 128-t blocks, no-max softmax ----------------
// Grid 1024: bid -> (bh = bid&127, tpair = bid>>7). Head-major so the 8 blocks of a
// head land on one XCD (round-robin dispatch) for K/V L2 locality.
// Each wave owns 2x16 t-columns (halves A/B). sP rows are wave-private and reused
// for the two halves back-to-back (in-wave DS ordering, no barrier).
__global__ __launch_bounds__(256, 4)
void attn_main(const __bf16* __restrict__ qh, const __bf16* __restrict__ qlo,
               const __bf16* __restrict__ kh, const __bf16* __restrict__ klo,
               const __bf16* __restrict__ vh,
               const float* __restrict__ mask, float* __restrict__ out)
{
  __shared__ __align__(16) __bf16 sKh[kTile];
  __shared__ __align__(16) __bf16 sKl[kTile];
  __shared__ __align__(16) __bf16 sVh[kTile];
  __shared__ __align__(16) __bf16 sP [kTile];
  __shared__ __align__(16) float  ms[64];

  const int tid  = threadIdx.x;
  const int lane = tid & 63;
  const int wave = tid >> 6;
  const int quad = lane >> 4;
  const int l15  = lane & 15;

  const int bid = blockIdx.x;
  const int bh  = bid & 127;       // head-major: blocks of one head share XCD
  const int tp  = bid >> 7;        // t-pair 0..7
  const int b   = bh >> 4;
  const int h   = bh & 15;
  const int t0  = tp * 128;

  const float* __restrict__ mrow = mask + (size_t)(h & 7) * kT;  // mask.repeat(n_heads,1)
  const size_t hbase = (size_t)bh * 16;

  // ---- stage both Q tiles (hi/lo) via DMA: one tensor-tile per wave ----
  {
    const __bf16* gsrc;
    __bf16* ldst;
    switch (wave) {
      case 0:  gsrc = qh  + (hbase + tp * 2 + 0) * kTile; ldst = sKh; break;
      case 1:  gsrc = qlo + (hbase + tp * 2 + 0) * kTile; ldst = sKl; break;
      case 2:  gsrc = qh  + (hbase + tp * 2 + 1) * kTile; ldst = sVh; break;
      default: gsrc = qlo + (hbase + tp * 2 + 1) * kTile; ldst = sP;  break;
    }
    const char* g = (const char*)gsrc + (size_t)lane * 16;
    char* l = (char*)ldst;
    #pragma unroll
    for (int i = 0; i < 9; ++i) async16(g + i * 1024, l + i * 1024);
  }
  __syncthreads();
  bf16x8 qhf[2][2], qlf[2][2];
  {
    const int row = (wave * 16 + l15) * kLS;
    #pragma unroll
    for (int kc = 0; kc < 2; ++kc) {
      qhf[0][kc] = *(const bf16x8*)&sKh[row + kc * 32 + quad * 8];
      qlf[0][kc] = *(const bf16x8*)&sKl[row + kc * 32 + quad * 8];
      qhf[1][kc] = *(const bf16x8*)&sVh[row + kc * 32 + quad * 8];
      qlf[1][kc] = *(const bf16x8*)&sP [row + kc * 32 + quad * 8];
    }
  }
  __syncthreads();

  f32x4 O0[4], O1[4];
  #pragma unroll
  for (int cc = 0; cc < 4; ++cc) {
    O0[cc] = (f32x4){0.f, 0.f, 0.f, 0.f};
    O1[cc] = (f32x4){0.f, 0.f, 0.f, 0.f};
  }
  float ls0 = 0.f, ls1 = 0.f;

  for (int st = 0; st < 16; ++st) {
    // ---- async stage K hi/lo + V: waves 0..2; wave 3 stages mask (pre-mul log2e) ----
    if (wave < 3) {
      const size_t ktb = (hbase + st) * kTile;
      const __bf16* gsrc = (wave == 0) ? kh + ktb : (wave == 1) ? klo + ktb : vh + ktb;
      char* ldst = (wave == 0) ? (char*)sKh : (wave == 1) ? (char*)sKl : (char*)sVh;
      const char* g = (const char*)gsrc + (size_t)lane * 16;
      #pragma unroll
      for (int i = 0; i < 9; ++i) async16(g + i * 1024, ldst + i * 1024);
    } else {
      ms[lane] = mrow[st * 64 + lane] * 1.44269504f;  // fold log2(e) into mask
    }
    __syncthreads();

    // ---- S^T = K^T·Q for both t-halves; K frags read once, feed 6 MFMA each ----
    f32x4 S0[4], S1[4];
    #pragma unroll
    for (int sc = 0; sc < 4; ++sc) {
      f32x4 a0 = (f32x4){0.f, 0.f, 0.f, 0.f};
      f32x4 a1 = (f32x4){0.f, 0.f, 0.f, 0.f};
      #pragma unroll
      for (int kc = 0; kc < 2; ++kc) {
        const int off = (sc * 16 + l15) * kLS + kc * 32 + quad * 8;
        bf16x8 k8 = *(const bf16x8*)&sKh[off];
        bf16x8 l8 = *(const bf16x8*)&sKl[off];
        a0 = MFMA16(k8, qlf[0][kc], a0);
        a0 = MFMA16(l8, qhf[0][kc], a0);
        a0 = MFMA16(k8, qhf[0][kc], a0);
        a1 = MFMA16(k8, qlf[1][kc], a1);
        a1 = MFMA16(l8, qhf[1][kc], a1);
        a1 = MFMA16(k8, qhf[1][kc], a1);
      }
      S0[sc] = a0;
      S1[sc] = a1;
    }

    // ---- p = exp2(S * ms'); wave-private sP rows reused for the two halves ----
    const int prow = (wave * 16 + l15) * kLS;
    bf16x8 pb0[2], pb1[2];
    #pragma unroll
    for (int sc = 0; sc < 4; ++sc) {
      f32x4 mv = *(const f32x4*)&ms[sc * 16 + quad * 4];
      bf16x4 ph;
      #pragma unroll
      for (int r = 0; r < 4; ++r) {
        float p = exp2f(S0[sc][r] * mv[r]);
        ls0 += p;
        ph[r] = (__bf16)p;
      }
      *(bf16x4*)&sP[prow + sc * 16 + quad * 4] = ph;
    }
    #pragma unroll
    for (int kc = 0; kc < 2; ++kc)
      pb0[kc] = *(const bf16x8*)&sP[prow + kc * 32 + quad * 8];
    #pragma unroll
    for (int sc = 0; sc < 4; ++sc) {
      f32x4 mv = *(const f32x4*)&ms[sc * 16 + quad * 4];
      bf16x4 ph;
      #pragma unroll
      for (int r = 0; r < 4; ++r) {
        float p = exp2f(S1[sc][r] * mv[r]);
        ls1 += p;
        ph[r] = (__bf16)p;
      }
      *(bf16x4*)&sP[prow + sc * 16 + quad * 4] = ph;  // WAR: in-wave DS order
    }
    #pragma unroll
    for (int kc = 0; kc < 2; ++kc)
      pb1[kc] = *(const bf16x8*)&sP[prow + kc * 32 + quad * 8];

    // ---- O^T += V·P^T for both halves; V frags read once, feed 2 MFMA each ----
    #pragma unroll
    for (int cc = 0; cc < 4; ++cc) {
      #pragma unroll
      for (int kc = 0; kc < 2; ++kc) {
        const int off = (cc * 16 + l15) * kLS + kc * 32 + quad * 8;
        bf16x8 v8 = *(const bf16x8*)&sVh[off];
        O0[cc] = MFMA16(v8, pb0[kc], O0[cc]);
        O1[cc] = MFMA16(v8, pb1[kc], O1[cc]);
      }
    }
    __syncthreads();  // before next tile's DMA overwrites K/V
  }

  // ---- epilogue: reduce denominators across quads, write both halves ----
  ls0 += __shfl_xor(ls0, 16);
  ls0 += __shfl_xor(ls0, 32);
  ls1 += __shfl_xor(ls1, 16);
  ls1 += __shfl_xor(ls1, 32);
  const float inv0 = 1.0f / ls0;
  const float inv1 = 1.0f / ls1;
  const int tcol = t0 + wave * 16 + l15;
  float* __restrict__ obase = out + (size_t)b * (1024 * 1024) + (size_t)(h * 64) * kT;
  #pragma unroll
  for (int cc = 0; cc < 4; ++cc) {
    #pragma unroll
    for (int r = 0; r < 4; ++r) {
      const int c = cc * 16 + quad * 4 + r;
      obase[(size_t)c * kT + tcol]      = O0[cc][r] * inv0;
      obase[(size_t)c * kT + tcol + 64] = O1[cc][r] * inv1;
    }
  }
}

// ---------------- Fallback (round-2 passing kernel, used if ws too small) ----------------
__global__ __launch_bounds__(256, 2)
void attn_fused(const float* __restrict__ qkv, const float* __restrict__ mask,
                float* __restrict__ out)
{
  __shared__ __align__(16) __bf16 Ahi[64 * kLS];
  __shared__ __align__(16) __bf16 Alo[64 * kLS];
  __shared__ __align__(16) __bf16 Vhi[64 * kLS];
  __shared__ __align__(16) __bf16 Vlo[64 * kLS];
  __shared__ __align__(16) __bf16 Phi[64 * kLS];
  __shared__ __align__(16) __bf16 Plo[64 * kLS];
  __shared__ __align__(16) float  ms[64];

  const int tid  = threadIdx.x;
  const int lane = tid & 63;
  const int wave = tid >> 6;
  const int quad = lane >> 4;
  const int l15  = lane & 15;

  const int bid = blockIdx.x;
  const int bh  = bid >> 4;
  const int tb  = bid & 15;
  const int b   = bh >> 4;
  const int h   = bh & 15;
  const int t0  = tb * 64;

  const float* __restrict__ qbase = qkv + (size_t)(b * 3072 + h * 64) * kT;
  const float* __restrict__ kbase = qkv + (size_t)(b * 3072 + 1024 + h * 64) * kT;
  const float* __restrict__ vbase = qkv + (size_t)(b * 3072 + 2048 + h * 64) * kT;
  const float* __restrict__ mrow  = mask + (size_t)(h & 7) * kT;

  const int sl = tid & 63;
  const int cg = tid >> 6;

  #pragma unroll
  for (int i = 0; i < 16; ++i) {
    const int c = cg * 16 + i;
    float v  = qbase[(size_t)c * kT + t0 + sl] * 0.125f;
    __bf16 hi = (__bf16)v;
    Ahi[sl * kLS + c] = hi;
    Alo[sl * kLS + c] = (__bf16)(v - (float)hi);
  }
  __syncthreads();

  bf16x8 qh[2], ql[2];
  {
    const int row = (wave * 16 + l15) * kLS;
    #pragma unroll
    for (int kc = 0; kc < 2; ++kc) {
      qh[kc] = *(const bf16x8*)&Ahi[row + kc * 32 + quad * 8];
      ql[kc] = *(const bf16x8*)&Alo[row + kc * 32 + quad * 8];
    }
  }
  __syncthreads();

  f32x4 O[4];
  #pragma unroll
  for (int cc = 0; cc < 4; ++cc) O[cc] = (f32x4){0.f, 0.f, 0.f, 0.f};
  float m_run = -__builtin_inff();
  float l_run = 0.f;

  for (int s0 = 0; s0 < kT; s0 += 64) {
    #pragma unroll
    for (int i = 0; i < 16; ++i) {
      const int c = cg * 16 + i;
      float kv   = kbase[(size_t)c * kT + s0 + sl];
      __bf16 khi = (__bf16)kv;
      Ahi[sl * kLS + c] = khi;
      Alo[sl * kLS + c] = (__bf16)(kv - (float)khi);
      float vv   = vbase[(size_t)c * kT + s0 + sl];
      __bf16 vhi = (__bf16)vv;
      Vhi[c * kLS + sl] = vhi;
      Vlo[c * kLS + sl] = (__bf16)(vv - (float)vhi);
    }
    if (tid < 64) ms[tid] = mrow[s0 + tid];
    __syncthreads();

    f32x4 S[4];
    #pragma unroll
    for (int sc = 0; sc < 4; ++sc) {
      f32x4 acc = (f32x4){0.f, 0.f, 0.f, 0.f};
      #pragma unroll
      for (int kc = 0; kc < 2; ++kc) {
        const int off = (sc * 16 + l15) * kLS + kc * 32 + quad * 8;
        bf16x8 kh8 = *(const bf16x8*)&Ahi[off];
        bf16x8 kl8 = *(const bf16x8*)&Alo[off];
        acc = MFMA16(kh8, ql[kc], acc);
        acc = MFMA16(kl8, qh[kc], acc);
        acc = MFMA16(kh8, qh[kc], acc);
      }
      S[sc] = acc;
    }

    float x[16];
    float tmax = -__builtin_inff();
    #pragma unroll
    for (int sc = 0; sc < 4; ++sc) {
      f32x4 mv = *(const f32x4*)&ms[sc * 16 + quad * 4];
      #pragma unroll
      for (int r = 0; r < 4; ++r) {
        float xv = S[sc][r] * mv[r];
        x[sc * 4 + r] = xv;
        tmax = fmaxf(tmax, xv);
      }
    }
    tmax = fmaxf(tmax, __shfl_xor(tmax, 16));
    tmax = fmaxf(tmax, __shfl_xor(tmax, 32));
    const float mnew  = fmaxf(m_run, tmax);
    const float alpha = __expf(m_run - mnew);
    float tsum = 0.f;
    #pragma unroll
    for (int i = 0; i < 16; ++i) {
      float p = __expf(x[i] - mnew);
      x[i] = p;
      tsum += p;
    }
    tsum += __shfl_xor(tsum, 16);
    tsum += __shfl_xor(tsum, 32);
    l_run = l_run * alpha + tsum;
    m_run = mnew;
    #pragma unroll
    for (int cc = 0; cc < 4; ++cc) O[cc] = O[cc] * alpha;

    const int prow = (wave * 16 + l15) * kLS;
    #pragma unroll
    for (int sc = 0; sc < 4; ++sc) {
      bf16x4 ph, pl;
      #pragma unroll
      for (int r = 0; r < 4; ++r) {
        float p   = x[sc * 4 + r];
        __bf16 hi = (__bf16)p;
        ph[r] = hi;
        pl[r] = (__bf16)(p - (float)hi);
      }
      *(bf16x4*)&Phi[prow + sc * 16 + quad * 4] = ph;
      *(bf16x4*)&Plo[prow + sc * 16 + quad * 4] = pl;
    }
    __syncthreads();

    bf16x8 pbh[2], pbl[2];
    #pragma unroll
    for (int kc = 0; kc < 2; ++kc) {
      pbh[kc] = *(const bf16x8*)&Phi[prow + kc * 32 + quad * 8];
      pbl[kc] = *(const bf16x8*)&Plo[prow + kc * 32 + quad * 8];
    }
    #pragma unroll
    for (int cc = 0; cc < 4; ++cc) {
      #pragma unroll
      for (int kc = 0; kc < 2; ++kc) {
        const int off = (cc * 16 + l15) * kLS + kc * 32 + quad * 8;
        bf16x8 v8 = *(const bf16x8*)&Vhi[off];
        bf16x8 w8 = *(const bf16x8*)&Vlo[off];
        O[cc] = MFMA16(v8, pbl[kc], O[cc]);
        O[cc] = MFMA16(w8, pbh[kc], O[cc]);
        O[cc] = MFMA16(v8, pbh[kc], O[cc]);
      }
    }
    __syncthreads();
  }

  const float inv  = 1.0f / l_run;
  const int   tcol = t0 + wave * 16 + l15;
  float* __restrict__ obase = out + (size_t)b * (1024 * 1024) + (size_t)(h * 64) * kT;
  #pragma unroll
  for (int cc = 0; cc < 4; ++cc) {
    #pragma unroll
    for (int r = 0; r < 4; ++r) {
      const int c = cc * 16 + quad * 4 + r;
      obase[(size_t)c * kT + tcol] = O[cc][r] * inv;
    }
  }
}

extern "C" void kernel_launch(void* const* d_in, const int* in_sizes, int n_in,
                              void* d_out, int out_size, void* d_ws, size_t ws_size,
                              hipStream_t stream)
{
  const float* qkv  = (const float*)d_in[0];  // (8, 3072, 1024) fp32
  const float* mask = (const float*)d_in[1];  // (8, 1024) fp32
  float* out = (float*)d_out;                 // (8, 1024, 1024) fp32
  (void)in_sizes; (void)n_in; (void)out_size;

  if (ws_size >= 5 * kTensorBytes) {
    char* w = (char*)d_ws;
    __bf16* qh  = (__bf16*)(w + 0 * kTensorBytes);
    __bf16* qlo = (__bf16*)(w + 1 * kTensorBytes);
    __bf16* kh  = (__bf16*)(w + 2 * kTensorBytes);
    __bf16* klo = (__bf16*)(w + 3 * kTensorBytes);
    __bf16* vh  = (__bf16*)(w + 4 * kTensorBytes);
    prepass<<<dim3(2048), dim3(256), 0, stream>>>(qkv, qh, qlo, kh, klo, vh);
    attn_main<<<dim3(1024), dim3(256), 0, stream>>>(qh, qlo, kh, klo, vh, mask, out);
  } else {
    attn_fused<<<dim3(2048), dim3(256), 0, stream>>>(qkv, mask, out);
  }
}

// Round 6
// 260.131 us; speedup vs baseline: 1.0594x; 1.0594x over previous
//
#include <hip/hip_runtime.h>
#include <stdint.h>
#include <math.h>

typedef float  f32x4  __attribute__((ext_vector_type(4)));
typedef __bf16 bf16x8 __attribute__((ext_vector_type(8)));
typedef __bf16 bf16x4 __attribute__((ext_vector_type(4)));

#define MFMA16(a, b, c) __builtin_amdgcn_mfma_f32_16x16x32_bf16((a), (b), (c), 0, 0, 0)

static constexpr int kT    = 1024;
static constexpr int kLS   = 72;            // padded row stride in bf16 (144 B, 16B-aligned)
static constexpr int kTile = 64 * kLS;      // 4608 el = 9216 B per 64x64 tile
static constexpr size_t kTensorEl    = (size_t)128 * 16 * kTile;   // 9,437,184 el
static constexpr size_t kTensorBytes = kTensorEl * 2;              // 18,874,368 B

__device__ inline void async16(const void* g, void* l) {
  __builtin_amdgcn_global_load_lds(
      (const __attribute__((address_space(1))) void*)g,
      (__attribute__((address_space(3))) void*)l, 16, 0, 0);
}

// ---------------- Prepass: fp32 -> bf16 (Q/K hi+lo split, V hi only) ----------------
// Folds: Q *= 0.125*log2(e)  (so MFMA output is the exp2 argument),
//        K *= mask[s]        (mask depends only on s: S*m == (m*K)^T Q).
// Layout per tensor: [bh 128][tile 16][row 64][kLS 72] bf16.
// Q^T/K^T rows = t|s, cols = c (transposed via LDS). V rows = c, cols = s (direct).
__global__ __launch_bounds__(256, 4)
void prepass(const float* __restrict__ qkv, const float* __restrict__ mask,
             __bf16* __restrict__ qh, __bf16* __restrict__ qlo,
             __bf16* __restrict__ kh, __bf16* __restrict__ klo,
             __bf16* __restrict__ vh)
{
  __shared__ float tq[64 * 65];   // fp32 staging for transpose (stride 65: conflict-free)
  __shared__ float tk[64 * 65];
  const int tid = threadIdx.x;
  const int bid = blockIdx.x, bh = bid >> 4, tile = bid & 15;
  const int b = bh >> 4, h = bh & 15, t0 = tile * 64;
  const float* __restrict__ qb = qkv + (size_t)(b * 3072 + h * 64) * kT;
  const float* __restrict__ kb = qkv + (size_t)(b * 3072 + 1024 + h * 64) * kT;
  const float* __restrict__ vb = qkv + (size_t)(b * 3072 + 2048 + h * 64) * kT;
  const float* __restrict__ mrow = mask + (size_t)(h & 7) * kT;  // mask.repeat(n_heads,1)
  const size_t tbase = ((size_t)bh * 16 + tile) * kTile;

  // load phase: float4 per thread; V converts+stores directly (t contiguous)
  const int t4   = (tid & 15) * 4;
  const int crow = tid >> 4;
  const f32x4 m4 = *(const f32x4*)&mrow[t0 + t4];   // same t-slice for all c rows
  #pragma unroll
  for (int i = 0; i < 4; ++i) {
    const int c = i * 16 + crow;
    f32x4 q4 = *(const f32x4*)&qb[(size_t)c * kT + t0 + t4];
    q4 *= 0.18033688f;                 // 0.125 * log2(e)
    *(f32x4*)&tq[c * 65 + t4] = q4;
    f32x4 k4 = *(const f32x4*)&kb[(size_t)c * kT + t0 + t4];
    k4 *= m4;                          // fold mask into K rows (s-axis)
    *(f32x4*)&tk[c * 65 + t4] = k4;
    f32x4 v4 = *(const f32x4*)&vb[(size_t)c * kT + t0 + t4];
    bf16x4 v4h;
    #pragma unroll
    for (int j = 0; j < 4; ++j) v4h[j] = (__bf16)v4[j];
    *(bf16x4*)&vh[tbase + c * kLS + t4] = v4h;
  }
  __syncthreads();

  // transpose phase: b64 stores, 4 consecutive c per lane
  const int c0 = tid & 15;
  const int rr = tid >> 4;
  #pragma unroll
  for (int i = 0; i < 4; ++i) {
    const int row = i * 16 + rr;
    bf16x4 qh4, ql4, kh4, kl4;
    #pragma unroll
    for (int j = 0; j < 4; ++j) {
      float q = tq[(c0 * 4 + j) * 65 + row];
      __bf16 qhi = (__bf16)q;
      qh4[j] = qhi; ql4[j] = (__bf16)(q - (float)qhi);
      float k = tk[(c0 * 4 + j) * 65 + row];
      __bf16 khi = (__bf16)k;
      kh4[j] = khi; kl4[j] = (__bf16)(k - (float)khi);
    }
    const size_t o = tbase + row * kLS + c0 * 4;
    *(bf16x4*)&qh [o] = qh4;
    *(bf16x4*)&qlo[o] = ql4;
    *(bf16x4*)&kh [o] = kh4;
    *(bf16x4*)&klo[o] = kl4;
  }
}

// ---------------- Main: flash attention, 128-t blocks, VALU-minimal softmax ----------------
// MFMA output == exp2 argument (mask & scales folded at prepass). Denominator via
// ones-MFMA: l[t] = (1^T P)[t] accumulated in a C-frag — no per-lane adds, no shuffles.
__global__ __launch_bounds__(256, 4)
void attn_main(const __bf16* __restrict__ qh, const __bf16* __restrict__ qlo,
               const __bf16* __restrict__ kh, const __bf16* __restrict__ klo,
               const __bf16* __restrict__ vh, float* __restrict__ out)
{
  __shared__ __align__(16) __bf16 sKh[kTile];
  __shared__ __align__(16) __bf16 sKl[kTile];
  __shared__ __align__(16) __bf16 sVh[kTile];
  __shared__ __align__(16) __bf16 sP [kTile];

  const int tid  = threadIdx.x;
  const int lane = tid & 63;
  const int wave = tid >> 6;
  const int quad = lane >> 4;
  const int l15  = lane & 15;

  const int bid = blockIdx.x;
  const int bh  = bid & 127;       // head-major: blocks of one head share XCD
  const int tp  = bid >> 7;        // t-pair 0..7
  const int b   = bh >> 4;
  const int h   = bh & 15;
  const int t0  = tp * 128;

  const size_t hbase = (size_t)bh * 16;

  bf16x8 ones8;
  #pragma unroll
  for (int j = 0; j < 8; ++j) ones8[j] = (__bf16)1.0f;

  // ---- stage both Q tiles (hi/lo) via DMA: one tensor-tile per wave ----
  {
    const __bf16* gsrc;
    __bf16* ldst;
    switch (wave) {
      case 0:  gsrc = qh  + (hbase + tp * 2 + 0) * kTile; ldst = sKh; break;
      case 1:  gsrc = qlo + (hbase + tp * 2 + 0) * kTile; ldst = sKl; break;
      case 2:  gsrc = qh  + (hbase + tp * 2 + 1) * kTile; ldst = sVh; break;
      default: gsrc = qlo + (hbase + tp * 2 + 1) * kTile; ldst = sP;  break;
    }
    const char* g = (const char*)gsrc + (size_t)lane * 16;
    char* l = (char*)ldst;
    #pragma unroll
    for (int i = 0; i < 9; ++i) async16(g + i * 1024, l + i * 1024);
  }
  __syncthreads();
  bf16x8 qhf[2][2], qlf[2][2];
  {
    const int row = (wave * 16 + l15) * kLS;
    #pragma unroll
    for (int kc = 0; kc < 2; ++kc) {
      qhf[0][kc] = *(const bf16x8*)&sKh[row + kc * 32 + quad * 8];
      qlf[0][kc] = *(const bf16x8*)&sKl[row + kc * 32 + quad * 8];
      qhf[1][kc] = *(const bf16x8*)&sVh[row + kc * 32 + quad * 8];
      qlf[1][kc] = *(const bf16x8*)&sP [row + kc * 32 + quad * 8];
    }
  }
  __syncthreads();

  f32x4 O0[4], O1[4];
  #pragma unroll
  for (int cc = 0; cc < 4; ++cc) {
    O0[cc] = (f32x4){0.f, 0.f, 0.f, 0.f};
    O1[cc] = (f32x4){0.f, 0.f, 0.f, 0.f};
  }
  f32x4 L0 = (f32x4){0.f, 0.f, 0.f, 0.f};
  f32x4 L1 = (f32x4){0.f, 0.f, 0.f, 0.f};

  for (int st = 0; st < 16; ++st) {
    // ---- async stage K hi/lo + V: one tensor per wave (wave 3 idle) ----
    if (wave < 3) {
      const size_t ktb = (hbase + st) * kTile;
      const __bf16* gsrc = (wave == 0) ? kh + ktb : (wave == 1) ? klo + ktb : vh + ktb;
      char* ldst = (wave == 0) ? (char*)sKh : (wave == 1) ? (char*)sKl : (char*)sVh;
      const char* g = (const char*)gsrc + (size_t)lane * 16;
      #pragma unroll
      for (int i = 0; i < 9; ++i) async16(g + i * 1024, ldst + i * 1024);
    }
    __syncthreads();

    // ---- S = exp2-args for both t-halves; K frags read once ----
    f32x4 S0[4], S1[4];
    #pragma unroll
    for (int sc = 0; sc < 4; ++sc) {
      f32x4 a0 = (f32x4){0.f, 0.f, 0.f, 0.f};
      f32x4 a1 = (f32x4){0.f, 0.f, 0.f, 0.f};
      #pragma unroll
      for (int kc = 0; kc < 2; ++kc) {
        const int off = (sc * 16 + l15) * kLS + kc * 32 + quad * 8;
        bf16x8 k8 = *(const bf16x8*)&sKh[off];
        bf16x8 l8 = *(const bf16x8*)&sKl[off];
        a0 = MFMA16(k8, qlf[0][kc], a0);
        a0 = MFMA16(l8, qhf[0][kc], a0);
        a0 = MFMA16(k8, qhf[0][kc], a0);
        a1 = MFMA16(k8, qlf[1][kc], a1);
        a1 = MFMA16(l8, qhf[1][kc], a1);
        a1 = MFMA16(k8, qhf[1][kc], a1);
      }
      S0[sc] = a0;
      S1[sc] = a1;
    }

    const int prow = (wave * 16 + l15) * kLS;

    // ---- softmax half A: pure exp2 + convert + wave-private sP rows ----
    #pragma unroll
    for (int sc = 0; sc < 4; ++sc) {
      bf16x4 ph;
      #pragma unroll
      for (int r = 0; r < 4; ++r) ph[r] = (__bf16)exp2f(S0[sc][r]);
      *(bf16x4*)&sP[prow + sc * 16 + quad * 4] = ph;
    }
    bf16x8 pb0[2];
    #pragma unroll
    for (int kc = 0; kc < 2; ++kc)
      pb0[kc] = *(const bf16x8*)&sP[prow + kc * 32 + quad * 8];
    L0 = MFMA16(ones8, pb0[0], L0);     // l[t] += sum_s P (denominator, no VALU)
    L0 = MFMA16(ones8, pb0[1], L0);

    // ---- PV half A (MFMA) — independent of softmax half B (trans/VALU): overlap ----
    #pragma unroll
    for (int cc = 0; cc < 4; ++cc) {
      #pragma unroll
      for (int kc = 0; kc < 2; ++kc) {
        const int off = (cc * 16 + l15) * kLS + kc * 32 + quad * 8;
        bf16x8 v8 = *(const bf16x8*)&sVh[off];
        O0[cc] = MFMA16(v8, pb0[kc], O0[cc]);
      }
    }

    // ---- softmax half B (sP rows reused: in-wave DS order after pb0 reads) ----
    #pragma unroll
    for (int sc = 0; sc < 4; ++sc) {
      bf16x4 ph;
      #pragma unroll
      for (int r = 0; r < 4; ++r) ph[r] = (__bf16)exp2f(S1[sc][r]);
      *(bf16x4*)&sP[prow + sc * 16 + quad * 4] = ph;
    }
    bf16x8 pb1[2];
    #pragma unroll
    for (int kc = 0; kc < 2; ++kc)
      pb1[kc] = *(const bf16x8*)&sP[prow + kc * 32 + quad * 8];
    L1 = MFMA16(ones8, pb1[0], L1);
    L1 = MFMA16(ones8, pb1[1], L1);

    // ---- PV half B ----
    #pragma unroll
    for (int cc = 0; cc < 4; ++cc) {
      #pragma unroll
      for (int kc = 0; kc < 2; ++kc) {
        const int off = (cc * 16 + l15) * kLS + kc * 32 + quad * 8;
        bf16x8 v8 = *(const bf16x8*)&sVh[off];
        O1[cc] = MFMA16(v8, pb1[kc], O1[cc]);
      }
    }
    __syncthreads();  // before next tile's DMA overwrites K/V
  }

  // ---- epilogue: L frag already holds l[t] in every reg (col = t = l15) ----
  const float inv0 = 1.0f / L0[0];
  const float inv1 = 1.0f / L1[0];
  const int tcol = t0 + wave * 16 + l15;
  float* __restrict__ obase = out + (size_t)b * (1024 * 1024) + (size_t)(h * 64) * kT;
  #pragma unroll
  for (int cc = 0; cc < 4; ++cc) {
    #pragma unroll
    for (int r = 0; r < 4; ++r) {
      const int c = cc * 16 + quad * 4 + r;
      obase[(size_t)c * kT + tcol]      = O0[cc][r] * inv0;
      obase[(size_t)c * kT + tcol + 64] = O1[cc][r] * inv1;
    }
  }
}

// ---------------- Fallback (round-2 passing kernel, used if ws too small) ----------------
__global__ __launch_bounds__(256, 2)
void attn_fused(const float* __restrict__ qkv, const float* __restrict__ mask,
                float* __restrict__ out)
{
  __shared__ __align__(16) __bf16 Ahi[64 * kLS];
  __shared__ __align__(16) __bf16 Alo[64 * kLS];
  __shared__ __align__(16) __bf16 Vhi[64 * kLS];
  __shared__ __align__(16) __bf16 Vlo[64 * kLS];
  __shared__ __align__(16) __bf16 Phi[64 * kLS];
  __shared__ __align__(16) __bf16 Plo[64 * kLS];
  __shared__ __align__(16) float  ms[64];

  const int tid  = threadIdx.x;
  const int lane = tid & 63;
  const int wave = tid >> 6;
  const int quad = lane >> 4;
  const int l15  = lane & 15;

  const int bid = blockIdx.x;
  const int bh  = bid >> 4;
  const int tb  = bid & 15;
  const int b   = bh >> 4;
  const int h   = bh & 15;
  const int t0  = tb * 64;

  const float* __restrict__ qbase = qkv + (size_t)(b * 3072 + h * 64) * kT;
  const float* __restrict__ kbase = qkv + (size_t)(b * 3072 + 1024 + h * 64) * kT;
  const float* __restrict__ vbase = qkv + (size_t)(b * 3072 + 2048 + h * 64) * kT;
  const float* __restrict__ mrow  = mask + (size_t)(h & 7) * kT;

  const int sl = tid & 63;
  const int cg = tid >> 6;

  #pragma unroll
  for (int i = 0; i < 16; ++i) {
    const int c = cg * 16 + i;
    float v  = qbase[(size_t)c * kT + t0 + sl] * 0.125f;
    __bf16 hi = (__bf16)v;
    Ahi[sl * kLS + c] = hi;
    Alo[sl * kLS + c] = (__bf16)(v - (float)hi);
  }
  __syncthreads();

  bf16x8 qh[2], ql[2];
  {
    const int row = (wave * 16 + l15) * kLS;
    #pragma unroll
    for (int kc = 0; kc < 2; ++kc) {
      qh[kc] = *(const bf16x8*)&Ahi[row + kc * 32 + quad * 8];
      ql[kc] = *(const bf16x8*)&Alo[row + kc * 32 + quad * 8];
    }
  }
  __syncthreads();

  f32x4 O[4];
  #pragma unroll
  for (int cc = 0; cc < 4; ++cc) O[cc] = (f32x4){0.f, 0.f, 0.f, 0.f};
  float m_run = -__builtin_inff();
  float l_run = 0.f;

  for (int s0 = 0; s0 < kT; s0 += 64) {
    #pragma unroll
    for (int i = 0; i < 16; ++i) {
      const int c = cg * 16 + i;
      float kv   = kbase[(size_t)c * kT + s0 + sl];
      __bf16 khi = (__bf16)kv;
      Ahi[sl * kLS + c] = khi;
      Alo[sl * kLS + c] = (__bf16)(kv - (float)khi);
      float vv   = vbase[(size_t)c * kT + s0 + sl];
      __bf16 vhi = (__bf16)vv;
      Vhi[c * kLS + sl] = vhi;
      Vlo[c * kLS + sl] = (__bf16)(vv - (float)vhi);
    }
    if (tid < 64) ms[tid] = mrow[s0 + tid];
    __syncthreads();

    f32x4 S[4];
    #pragma unroll
    for (int sc = 0; sc < 4; ++sc) {
      f32x4 acc = (f32x4){0.f, 0.f, 0.f, 0.f};
      #pragma unroll
      for (int kc = 0; kc < 2; ++kc) {
        const int off = (sc * 16 + l15) * kLS + kc * 32 + quad * 8;
        bf16x8 kh8 = *(const bf16x8*)&Ahi[off];
        bf16x8 kl8 = *(const bf16x8*)&Alo[off];
        acc = MFMA16(kh8, ql[kc], acc);
        acc = MFMA16(kl8, qh[kc], acc);
        acc = MFMA16(kh8, qh[kc], acc);
      }
      S[sc] = acc;
    }

    float x[16];
    float tmax = -__builtin_inff();
    #pragma unroll
    for (int sc = 0; sc < 4; ++sc) {
      f32x4 mv = *(const f32x4*)&ms[sc * 16 + quad * 4];
      #pragma unroll
      for (int r = 0; r < 4; ++r) {
        float xv = S[sc][r] * mv[r];
        x[sc * 4 + r] = xv;
        tmax = fmaxf(tmax, xv);
      }
    }
    tmax = fmaxf(tmax, __shfl_xor(tmax, 16));
    tmax = fmaxf(tmax, __shfl_xor(tmax, 32));
    const float mnew  = fmaxf(m_run, tmax);
    const float alpha = __expf(m_run - mnew);
    float tsum = 0.f;
    #pragma unroll
    for (int i = 0; i < 16; ++i) {
      float p = __expf(x[i] - mnew);
      x[i] = p;
      tsum += p;
    }
    tsum += __shfl_xor(tsum, 16);
    tsum += __shfl_xor(tsum, 32);
    l_run = l_run * alpha + tsum;
    m_run = mnew;
    #pragma unroll
    for (int cc = 0; cc < 4; ++cc) O[cc] = O[cc] * alpha;

    const int prow = (wave * 16 + l15) * kLS;
    #pragma unroll
    for (int sc = 0; sc < 4; ++sc) {
      bf16x4 ph, pl;
      #pragma unroll
      for (int r = 0; r < 4; ++r) {
        float p   = x[sc * 4 + r];
        __bf16 hi = (__bf16)p;
        ph[r] = hi;
        pl[r] = (__bf16)(p - (float)hi);
      }
      *(bf16x4*)&Phi[prow + sc * 16 + quad * 4] = ph;
      *(bf16x4*)&Plo[prow + sc * 16 + quad * 4] = pl;
    }
    __syncthreads();

    bf16x8 pbh[2], pbl[2];
    #pragma unroll
    for (int kc = 0; kc < 2; ++kc) {
      pbh[kc] = *(const bf16x8*)&Phi[prow + kc * 32 + quad * 8];
      pbl[kc] = *(const bf16x8*)&Plo[prow + kc * 32 + quad * 8];
    }
    #pragma unroll
    for (int cc = 0; cc < 4; ++cc) {
      #pragma unroll
      for (int kc = 0; kc < 2; ++kc) {
        const int off = (cc * 16 + l15) * kLS + kc * 32 + quad * 8;
        bf16x8 v8 = *(const bf16x8*)&Vhi[off];
        bf16x8 w8 = *(const bf16x8*)&Vlo[off];
        O[cc] = MFMA16(v8, pbl[kc], O[cc]);
        O[cc] = MFMA16(w8, pbh[kc], O[cc]);
        O[cc] = MFMA16(v8, pbh[kc], O[cc]);
      }
    }
    __syncthreads();
  }

  const float inv  = 1.0f / l_run;
  const int   tcol = t0 + wave * 16 + l15;
  float* __restrict__ obase = out + (size_t)b * (1024 * 1024) + (size_t)(h * 64) * kT;
  #pragma unroll
  for (int cc = 0; cc < 4; ++cc) {
    #pragma unroll
    for (int r = 0; r < 4; ++r) {
      const int c = cc * 16 + quad * 4 + r;
      obase[(size_t)c * kT + tcol] = O[cc][r] * inv;
    }
  }
}

extern "C" void kernel_launch(void* const* d_in, const int* in_sizes, int n_in,
                              void* d_out, int out_size, void* d_ws, size_t ws_size,
                              hipStream_t stream)
{
  const float* qkv  = (const float*)d_in[0];  // (8, 3072, 1024) fp32
  const float* mask = (const float*)d_in[1];  // (8, 1024) fp32
  float* out = (float*)d_out;                 // (8, 1024, 1024) fp32
  (void)in_sizes; (void)n_in; (void)out_size;

  if (ws_size >= 5 * kTensorBytes) {
    char* w = (char*)d_ws;
    __bf16* qh  = (__bf16*)(w + 0 * kTensorBytes);
    __bf16* qlo = (__bf16*)(w + 1 * kTensorBytes);
    __bf16* kh  = (__bf16*)(w + 2 * kTensorBytes);
    __bf16* klo = (__bf16*)(w + 3 * kTensorBytes);
    __bf16* vh  = (__bf16*)(w + 4 * kTensorBytes);
    prepass<<<dim3(2048), dim3(256), 0, stream>>>(qkv, mask, qh, qlo, kh, klo, vh);
    attn_main<<<dim3(1024), dim3(256), 0, stream>>>(qh, qlo, kh, klo, vh, out);
  } else {
    attn_fused<<<dim3(2048), dim3(256), 0, stream>>>(qkv, mask, out);
  }
}